// Round 5
// 138.466 us; speedup vs baseline: 1.0237x; 1.0237x over previous
//
#include <hip/hip_runtime.h>

// Problem constants (compile-time, from reference):
//   B=2, D=H=W=160, C=2, N_LABELS=25, MAX_LABEL=48
//   voxels/batch V = 160^3 = 4,096,000 ; total voxels = 8,192,000
#define VPB   4096000
#define NLAB  25
#define TOTAL_VOX 8192000

// GEN_LABELS = {0,2,3,4,5,7,8,10,11,12,13,14,15,16,17,18,24,26,28,41,42,43,44,46,47}
// encoded as a 48-bit mask; row(label) = popcount(mask & ((1<<label)-1)).
// Verified against the previous c_lut: e.g. row(2)=1, row(18)=15, row(24)=16,
// row(41)=19, row(47)=24. popcount(mask)=25.
#define GEN_MASK 0x0000DE001507FDBDull

// Round-10 (4th resubmit after broker timeouts): kill the block-level
// coupling. The per-batch table is 48 float4 entries == one per lane, so it
// lives in 4 VGPRs/lane and the per-voxel gather is 8 ds_bpermute (__shfl)
// ops. No LDS, no __syncthreads, no 96-thread table-build branch, no bank
// conflicts: every wave is fully independent -> shorter wave lifetime,
// which r1/r4/r5/r9 showed is the binding constraint (wave-completion-rate
// bound, not BW bound).
// Round-3 lesson kept: NO nontemporal stores (1.74x WRITE_SIZE amplification).
__global__ __launch_bounds__(256) void gmm_sample_kernel(
    const int*   __restrict__ labels,   // [B*V] (trailing dim 1 squeezed)
    const float* __restrict__ means,    // [B, 25, 2]
    const float* __restrict__ stds,     // [B, 25, 2]
    const float* __restrict__ noise,    // [B*V, 2]
    float*       __restrict__ out)      // [B*V, 2]
{
    const int tid = threadIdx.x;
    const int g   = blockIdx.x * 256 + tid;     // thread id, < 4,096,000
    const int v0  = g << 1;                     // first voxel, < 8,192,000

    // ---- streaming loads issue first, in flight during table load ----
    const int2   lab = *(const int2*)  (labels + v0);
    const float4 n0  = *(const float4*)(noise + ((size_t)v0 << 1));

    // ---- per-wave register table: lane l holds (m0,m1,s0,s1) for label
    //      VALUE l (l in 0..47; input labels are always in GEN_LABELS) ----
    const int lane = tid & 63;
    int row = (int)__popcll(GEN_MASK & ((1ull << lane) - 1ull));
    row = row < NLAB ? row : NLAB - 1;          // lanes 48-63: clamp (data unused)

    // Batch boundary (4,096,000) = block 8000 * 512 exactly -> whole block
    // (and both voxels of each thread) lie in one batch.
    const int boff = (v0 >= VPB) ? NLAB : 0;
    const float2 m = *(const float2*)(means + ((boff + row) << 1));  // L1/L2-hot 400 B
    const float2 s = *(const float2*)(stds  + ((boff + row) << 1));

    // ---- gather = intra-wave shuffle (ds_bpermute), conflict-free ----
    const float e0x = __shfl(m.x, lab.x, 64);
    const float e0y = __shfl(m.y, lab.x, 64);
    const float e0z = __shfl(s.x, lab.x, 64);
    const float e0w = __shfl(s.y, lab.x, 64);
    const float e1x = __shfl(m.x, lab.y, 64);
    const float e1y = __shfl(m.y, lab.y, 64);
    const float e1z = __shfl(s.x, lab.y, 64);
    const float e1w = __shfl(s.y, lab.y, 64);

    float4 o0;
    o0.x = fmaf(e0z, n0.x, e0x);
    o0.y = fmaf(e0w, n0.y, e0y);
    o0.z = fmaf(e1z, n0.z, e1x);
    o0.w = fmaf(e1w, n0.w, e1y);

    *(float4*)(out + ((size_t)v0 << 1)) = o0;
}

extern "C" void kernel_launch(void* const* d_in, const int* in_sizes, int n_in,
                              void* d_out, int out_size, void* d_ws, size_t ws_size,
                              hipStream_t stream) {
    const int*   labels = (const int*)  d_in[0];  // [2,160,160,160,1] int32
    const float* means  = (const float*)d_in[1];  // [2,25,2] f32
    const float* stds   = (const float*)d_in[2];  // [2,25,2] f32
    const float* noise  = (const float*)d_in[3];  // [2,160,160,160,2] f32
    float* out = (float*)d_out;                   // [2,160,160,160,2] f32

    const int threads = 256;
    const int total_threads = TOTAL_VOX / 2;      // 4,096,000
    const int blocks = total_threads / threads;   // 16000
    gmm_sample_kernel<<<blocks, threads, 0, stream>>>(labels, means, stds, noise, out);
}